// Round 1
// baseline (1387.167 us; speedup 1.0000x reference)
//
#include <hip/hip_runtime.h>

constexpr int NN = 50000;   // nodes
constexpr int NE = 600000;  // edges
constexpr int D  = 128;     // features
constexpr int NR = 8;       // relations

// ---------------- phase 1: per-(relation,dst) edge counts ----------------
__global__ __launch_bounds__(256) void count_kernel(const int* __restrict__ et,
                                                    const int* __restrict__ dst,
                                                    int* __restrict__ cnt) {
    int e = blockIdx.x * 256 + threadIdx.x;
    if (e < NE) atomicAdd(&cnt[et[e] * NN + dst[e]], 1);
}

// ---------------- phase 2: scatter mean contributions --------------------
// sums[(r-r0)*NN + dst][d] += x[src][d] / max(cnt[r*NN+dst], 1)
// 32 threads per edge, float4 per thread.
__global__ __launch_bounds__(256) void scatter_kernel(const float* __restrict__ x,
                                                      const int* __restrict__ src,
                                                      const int* __restrict__ dst,
                                                      const int* __restrict__ et,
                                                      const int* __restrict__ cnt,
                                                      float* __restrict__ sums,
                                                      int r0, int r1) {
    int gid = blockIdx.x * 256 + threadIdx.x;
    int e = gid >> 5;
    if (e >= NE) return;
    int r = et[e];
    if (r < r0 || r >= r1) return;
    int q  = gid & 31;
    int dn = dst[e];
    int c  = cnt[r * NN + dn];
    float inv = 1.0f / (float)(c > 0 ? c : 1);
    int s = src[e];
    float4 v = *(const float4*)(x + (size_t)s * D + (q << 2));
    float* o = sums + ((size_t)(r - r0) * NN + dn) * D + (q << 2);
    atomicAdd(o + 0, v.x * inv);
    atomicAdd(o + 1, v.y * inv);
    atomicAdd(o + 2, v.z * inv);
    atomicAdd(o + 3, v.w * inv);
}

// ---------------- phase 3: GEMM ------------------------------------------
// out[NN,128] (+)= A @ W  where A[n,k] = A[((k>>7)*NN + n)*128 + (k&127)]
// (relation-plane-blocked row-major) and W[k,j] = W[(k>>7)*16384 + (k&127)*128 + j].
// BM=64, BN=128, BK=32; 256 threads; 4x8 micro-tile per thread.
template <bool ACC, bool RELU, bool BIAS>
__global__ __launch_bounds__(256) void gemm_kernel(const float* __restrict__ A,
                                                   const float* __restrict__ W,
                                                   const float* __restrict__ bias,
                                                   float* __restrict__ out, int K) {
    __shared__ float Ast[32][72];   // [k][m], stride 72 -> conflict-free staging, aligned reads
    __shared__ float Bs[32][128];   // [k][j]

    const int tid = threadIdx.x;
    const int tx  = tid & 15;        // 0..15 -> cols tx*8..+7
    const int ty  = tid >> 4;        // 0..15 -> rows ty*4..+3
    const int m0  = blockIdx.x * 64;

    const int arow = tid >> 3;              // 0..31
    const int acol = (tid & 7) << 2;        // 0,4,...,28
    const int brow = tid >> 5;              // 0..7
    const int bcol = (tid & 31) << 2;       // 0..124

    float acc[4][8];
#pragma unroll
    for (int i = 0; i < 4; ++i)
#pragma unroll
        for (int j = 0; j < 8; ++j) acc[i][j] = 0.0f;

    for (int k0 = 0; k0 < K; k0 += 32) {
        const int rpl = k0 >> 7;
        const int kof = k0 & 127;
        const float* Ab = A + (size_t)rpl * NN * D + kof;
        const float* Wb = W + (size_t)rpl * D * D + (size_t)kof * D;

        __syncthreads();
#pragma unroll
        for (int p = 0; p < 2; ++p) {
            int row = arow + p * 32;
            int n = m0 + row;
            float4 v = make_float4(0.f, 0.f, 0.f, 0.f);
            if (n < NN) v = *(const float4*)(Ab + (size_t)n * D + acol);
            Ast[acol + 0][row] = v.x;
            Ast[acol + 1][row] = v.y;
            Ast[acol + 2][row] = v.z;
            Ast[acol + 3][row] = v.w;
        }
#pragma unroll
        for (int p = 0; p < 4; ++p) {
            int row = brow + p * 8;
            *(float4*)&Bs[row][bcol] = *(const float4*)(Wb + row * D + bcol);
        }
        __syncthreads();

#pragma unroll
        for (int kk = 0; kk < 32; ++kk) {
            float4 a  = *(const float4*)&Ast[kk][ty << 2];
            float4 b0 = *(const float4*)&Bs[kk][tx << 3];
            float4 b1 = *(const float4*)&Bs[kk][(tx << 3) + 4];
            float av[4] = {a.x, a.y, a.z, a.w};
            float bv[8] = {b0.x, b0.y, b0.z, b0.w, b1.x, b1.y, b1.z, b1.w};
#pragma unroll
            for (int i = 0; i < 4; ++i)
#pragma unroll
                for (int j = 0; j < 8; ++j) acc[i][j] += av[i] * bv[j];
        }
    }

#pragma unroll
    for (int i = 0; i < 4; ++i) {
        int n = m0 + (ty << 2) + i;
        if (n >= NN) continue;
        float* orow = out + (size_t)n * D + (tx << 3);
#pragma unroll
        for (int j = 0; j < 8; ++j) {
            float v = acc[i][j];
            if (ACC)  v += orow[j];
            if (BIAS) v += bias[(tx << 3) + j];
            if (RELU) v = fmaxf(v, 0.0f);
            orow[j] = v;
        }
    }
}

extern "C" void kernel_launch(void* const* d_in, const int* in_sizes, int n_in,
                              void* d_out, int out_size, void* d_ws, size_t ws_size,
                              hipStream_t stream) {
    const float* x      = (const float*)d_in[0];
    const int*   ei     = (const int*)d_in[1];   // [2, NE]
    const int*   et     = (const int*)d_in[2];   // [NE]
    const float* weight = (const float*)d_in[3]; // [NR, D, D]
    const float* root   = (const float*)d_in[4]; // [D, D]
    const float* bias   = (const float*)d_in[5]; // [D]
    float* out = (float*)d_out;
    const int* srcv = ei;
    const int* dstv = ei + NE;

    // workspace layout: [cnt : NR*NN ints][sums : C*NN*D floats]
    int* cnt = (int*)d_ws;
    size_t cnt_b  = (size_t)NR * NN * sizeof(int);
    size_t cnt_al = (cnt_b + 255) & ~(size_t)255;
    float* sums = (float*)((char*)d_ws + cnt_al);
    size_t per_rel = (size_t)NN * D * sizeof(float);   // 25.6 MB
    size_t avail = (ws_size > cnt_al) ? ws_size - cnt_al : 0;
    int C = (int)(avail / per_rel);
    if (C > NR) C = NR;
    if (C < 1)  C = 1;   // last-resort; assumes ws >= ~27 MB

    hipMemsetAsync(cnt, 0, cnt_b, stream);
    count_kernel<<<(NE + 255) / 256, 256, 0, stream>>>(et, dstv, cnt);

    dim3 ggrid((NN + 63) / 64);
    // out = x @ root + bias  (no ReLU yet)
    gemm_kernel<false, false, true><<<ggrid, 256, 0, stream>>>(x, root, bias, out, D);

    const int sblocks = (NE * 32 + 255) / 256;
    for (int r0 = 0; r0 < NR; r0 += C) {
        int r1 = r0 + C; if (r1 > NR) r1 = NR;
        hipMemsetAsync(sums, 0, (size_t)(r1 - r0) * per_rel, stream);
        scatter_kernel<<<sblocks, 256, 0, stream>>>(x, srcv, dstv, et, cnt, sums, r0, r1);
        const float* Wc = weight + (size_t)r0 * D * D;
        int Kc = (r1 - r0) * D;
        if (r1 == NR)
            gemm_kernel<true, true, false><<<ggrid, 256, 0, stream>>>(sums, Wc, nullptr, out, Kc);
        else
            gemm_kernel<true, false, false><<<ggrid, 256, 0, stream>>>(sums, Wc, nullptr, out, Kc);
    }
}

// Round 2
// 500.739 us; speedup vs baseline: 2.7702x; 2.7702x over previous
//
#include <hip/hip_runtime.h>

constexpr int NN = 50000;   // nodes
constexpr int NE = 600000;  // edges
constexpr int D  = 128;     // features
constexpr int NR = 8;       // relations

constexpr int SCAN_ELEMS = 1024;
constexpr int NBLK_SCAN  = (NN + SCAN_ELEMS - 1) / SCAN_ELEMS;   // 49

// ---------------- phase 1: per-dst edge counts ---------------------------
__global__ __launch_bounds__(256) void count_dst(const int* __restrict__ dst,
                                                 int* __restrict__ cnt_d) {
    int e = blockIdx.x * 256 + threadIdx.x;
    if (e < NE) atomicAdd(&cnt_d[dst[e]], 1);
}

// ---------------- phase 2: exclusive scan of cnt_d -> offs ---------------
__global__ __launch_bounds__(256) void scan1(const int* __restrict__ cnt,
                                             int* __restrict__ offs,
                                             int* __restrict__ bsums) {
    __shared__ int lds[256];
    int t = threadIdx.x;
    int base = blockIdx.x * SCAN_ELEMS + t * 4;
    int v0 = (base + 0 < NN) ? cnt[base + 0] : 0;
    int v1 = (base + 1 < NN) ? cnt[base + 1] : 0;
    int v2 = (base + 2 < NN) ? cnt[base + 2] : 0;
    int v3 = (base + 3 < NN) ? cnt[base + 3] : 0;
    int s = v0 + v1 + v2 + v3;
    lds[t] = s;
    __syncthreads();
    int val = s;
    for (int off = 1; off < 256; off <<= 1) {
        int tmp = (t >= off) ? lds[t - off] : 0;
        __syncthreads();
        val += tmp;
        lds[t] = val;
        __syncthreads();
    }
    int ex = val - s;   // exclusive within block
    if (base + 0 < NN) offs[base + 0] = ex;
    if (base + 1 < NN) offs[base + 1] = ex + v0;
    if (base + 2 < NN) offs[base + 2] = ex + v0 + v1;
    if (base + 3 < NN) offs[base + 3] = ex + v0 + v1 + v2;
    if (t == 255) bsums[blockIdx.x] = val;   // block total
}

__global__ __launch_bounds__(64) void scan2(int* __restrict__ bsums) {
    __shared__ int lds[64];
    int t = threadIdx.x;
    int v = (t < NBLK_SCAN) ? bsums[t] : 0;
    lds[t] = v;
    __syncthreads();
    int val = v;
    for (int off = 1; off < 64; off <<= 1) {
        int tmp = (t >= off) ? lds[t - off] : 0;
        __syncthreads();
        val += tmp;
        lds[t] = val;
        __syncthreads();
    }
    if (t < NBLK_SCAN) bsums[t] = val - v;   // exclusive
}

__global__ __launch_bounds__(256) void scan3(int* __restrict__ offs,
                                             const int* __restrict__ bsums) {
    int i = blockIdx.x * 256 + threadIdx.x;
    if (i < NN) offs[i] += bsums[i >> 10];
    if (i == 0) offs[NN] = NE;
}

// ---------------- phase 3: bin edges by dst ------------------------------
__global__ __launch_bounds__(256) void fill_bins(const int* __restrict__ src,
                                                 const int* __restrict__ dst,
                                                 const int* __restrict__ et,
                                                 const int* __restrict__ offs,
                                                 int* __restrict__ cur,
                                                 int* __restrict__ ebin) {
    int e = blockIdx.x * 256 + threadIdx.x;
    if (e >= NE) return;
    int d = dst[e];
    int idx = offs[d] + atomicAdd(&cur[d], 1);
    ebin[idx] = (et[e] << 16) | src[e];   // src < 50000 < 2^16
}

// ---------------- phase 4: per-dst aggregation (no atomics) --------------
// one block per dst node; 128 threads = feature columns; 8 relation buckets
// in LDS. Thread t exclusively owns LDS column t -> no races, no barriers
// in the edge loop.
__global__ __launch_bounds__(128) void aggregate_kernel(const float* __restrict__ x,
                                                        const int* __restrict__ offs,
                                                        const int* __restrict__ ebin,
                                                        float* __restrict__ sums,
                                                        int r0, int r1) {
    __shared__ float acc[NR * D];
    __shared__ int   scnt[NR];
    __shared__ float sinv[NR];
    int n = blockIdx.x;
    int t = threadIdx.x;
    for (int i = t; i < NR * D; i += 128) acc[i] = 0.0f;
    if (t < NR) scnt[t] = 0;
    __syncthreads();
    int beg = offs[n], end = offs[n + 1];
    for (int p = beg; p < end; ++p) {
        int pk = ebin[p];
        int r  = pk >> 16;
        int s  = pk & 0xffff;
        if (t == 0) scnt[r]++;
        if (r >= r0 && r < r1)                      // uniform branch
            acc[r * D + t] += x[(size_t)s * D + t]; // coalesced 512B row read
    }
    __syncthreads();
    if (t < NR) sinv[t] = 1.0f / (float)(scnt[t] > 0 ? scnt[t] : 1);
    __syncthreads();
    for (int r = r0; r < r1; ++r)
        sums[((size_t)(r - r0) * NN + n) * D + t] = acc[r * D + t] * sinv[r];
}

// ---------------- phase 5: GEMM ------------------------------------------
// out[NN,128] (+)= A @ W  where A is relation-plane-blocked row-major and
// W[k,j] = W[(k>>7)*16384 + (k&127)*128 + j].  BM=64, BN=128, BK=32.
template <bool ACC, bool RELU, bool BIAS>
__global__ __launch_bounds__(256) void gemm_kernel(const float* __restrict__ A,
                                                   const float* __restrict__ W,
                                                   const float* __restrict__ bias,
                                                   float* __restrict__ out, int K) {
    __shared__ float Ast[32][72];
    __shared__ float Bs[32][128];

    const int tid = threadIdx.x;
    const int tx  = tid & 15;
    const int ty  = tid >> 4;
    const int m0  = blockIdx.x * 64;

    const int arow = tid >> 3;
    const int acol = (tid & 7) << 2;
    const int brow = tid >> 5;
    const int bcol = (tid & 31) << 2;

    float acc[4][8];
#pragma unroll
    for (int i = 0; i < 4; ++i)
#pragma unroll
        for (int j = 0; j < 8; ++j) acc[i][j] = 0.0f;

    for (int k0 = 0; k0 < K; k0 += 32) {
        const int rpl = k0 >> 7;
        const int kof = k0 & 127;
        const float* Ab = A + (size_t)rpl * NN * D + kof;
        const float* Wb = W + (size_t)rpl * D * D + (size_t)kof * D;

        __syncthreads();
#pragma unroll
        for (int p = 0; p < 2; ++p) {
            int row = arow + p * 32;
            int n = m0 + row;
            float4 v = make_float4(0.f, 0.f, 0.f, 0.f);
            if (n < NN) v = *(const float4*)(Ab + (size_t)n * D + acol);
            Ast[acol + 0][row] = v.x;
            Ast[acol + 1][row] = v.y;
            Ast[acol + 2][row] = v.z;
            Ast[acol + 3][row] = v.w;
        }
#pragma unroll
        for (int p = 0; p < 4; ++p) {
            int row = brow + p * 8;
            *(float4*)&Bs[row][bcol] = *(const float4*)(Wb + row * D + bcol);
        }
        __syncthreads();

#pragma unroll
        for (int kk = 0; kk < 32; ++kk) {
            float4 a  = *(const float4*)&Ast[kk][ty << 2];
            float4 b0 = *(const float4*)&Bs[kk][tx << 3];
            float4 b1 = *(const float4*)&Bs[kk][(tx << 3) + 4];
            float av[4] = {a.x, a.y, a.z, a.w};
            float bv[8] = {b0.x, b0.y, b0.z, b0.w, b1.x, b1.y, b1.z, b1.w};
#pragma unroll
            for (int i = 0; i < 4; ++i)
#pragma unroll
                for (int j = 0; j < 8; ++j) acc[i][j] += av[i] * bv[j];
        }
    }

#pragma unroll
    for (int i = 0; i < 4; ++i) {
        int n = m0 + (ty << 2) + i;
        if (n >= NN) continue;
        float* orow = out + (size_t)n * D + (tx << 3);
#pragma unroll
        for (int j = 0; j < 8; ++j) {
            float v = acc[i][j];
            if (ACC)  v += orow[j];
            if (BIAS) v += bias[(tx << 3) + j];
            if (RELU) v = fmaxf(v, 0.0f);
            orow[j] = v;
        }
    }
}

extern "C" void kernel_launch(void* const* d_in, const int* in_sizes, int n_in,
                              void* d_out, int out_size, void* d_ws, size_t ws_size,
                              hipStream_t stream) {
    const float* x      = (const float*)d_in[0];
    const int*   ei     = (const int*)d_in[1];
    const int*   et     = (const int*)d_in[2];
    const float* weight = (const float*)d_in[3];
    const float* root   = (const float*)d_in[4];
    const float* bias   = (const float*)d_in[5];
    float* out = (float*)d_out;
    const int* srcv = ei;
    const int* dstv = ei + NE;

    // workspace layout: [cnt_d NN][cur NN][offs NN+1][bsums 64][ebin NE][sums]
    int* cnt_d = (int*)d_ws;
    int* cur   = cnt_d + NN;
    int* offs  = cur + NN;
    int* bsums = offs + NN + 1;
    int* ebin  = bsums + 64;
    size_t fixed_b = ((char*)(ebin + NE) - (char*)d_ws);
    size_t fixed_al = (fixed_b + 255) & ~(size_t)255;
    float* sums = (float*)((char*)d_ws + fixed_al);
    size_t per_rel = (size_t)NN * D * sizeof(float);   // 25.6 MB
    size_t avail = (ws_size > fixed_al) ? ws_size - fixed_al : 0;
    int C = (int)(avail / per_rel);
    if (C > NR) C = NR;
    if (C < 1)  C = 1;

    hipMemsetAsync(cnt_d, 0, 2 * NN * sizeof(int), stream);   // cnt_d + cur
    count_dst<<<(NE + 255) / 256, 256, 0, stream>>>(dstv, cnt_d);
    scan1<<<NBLK_SCAN, 256, 0, stream>>>(cnt_d, offs, bsums);
    scan2<<<1, 64, 0, stream>>>(bsums);
    scan3<<<(NN + 255) / 256, 256, 0, stream>>>(offs, bsums);
    fill_bins<<<(NE + 255) / 256, 256, 0, stream>>>(srcv, dstv, et, offs, cur, ebin);

    dim3 ggrid((NN + 63) / 64);
    gemm_kernel<false, false, true><<<ggrid, 256, 0, stream>>>(x, root, bias, out, D);

    for (int r0 = 0; r0 < NR; r0 += C) {
        int r1 = r0 + C; if (r1 > NR) r1 = NR;
        aggregate_kernel<<<NN, 128, 0, stream>>>(x, offs, ebin, sums, r0, r1);
        const float* Wc = weight + (size_t)r0 * D * D;
        int Kc = (r1 - r0) * D;
        if (r1 == NR)
            gemm_kernel<true, true, false><<<ggrid, 256, 0, stream>>>(sums, Wc, nullptr, out, Kc);
        else
            gemm_kernel<true, false, false><<<ggrid, 256, 0, stream>>>(sums, Wc, nullptr, out, Kc);
    }
}

// Round 3
// 279.738 us; speedup vs baseline: 4.9588x; 1.7900x over previous
//
#include <hip/hip_runtime.h>

constexpr int NN = 50000;   // nodes
constexpr int NE = 600000;  // edges
constexpr int D  = 128;     // features
constexpr int NR = 8;       // relations
constexpr int KT = (NR + 1) * D;   // 1152 total K (root plane + 8 relation planes)

constexpr int SCAN_ELEMS = 1024;
constexpr int NBLK_SCAN  = (NN + SCAN_ELEMS - 1) / SCAN_ELEMS;   // 49

typedef unsigned int   u32;
typedef unsigned short u16;
typedef float  f32x4 __attribute__((ext_vector_type(4)));
typedef short  s16x8 __attribute__((ext_vector_type(8)));

__device__ __forceinline__ u16 f2bf(float f) {
    u32 u = __float_as_uint(f);
    u32 r = (u + 0x7fffu + ((u >> 16) & 1u)) >> 16;   // RNE
    return (u16)r;
}

__device__ __forceinline__ void async_cp16(const void* g, void* l) {
    __builtin_amdgcn_global_load_lds(
        (const __attribute__((address_space(1))) u32*)g,
        (__attribute__((address_space(3))) u32*)l, 16, 0, 0);
}

// ---------------- phase 1: per-dst edge counts ---------------------------
__global__ __launch_bounds__(256) void count_dst(const int* __restrict__ dst,
                                                 int* __restrict__ cnt_d) {
    int e = blockIdx.x * 256 + threadIdx.x;
    if (e < NE) atomicAdd(&cnt_d[dst[e]], 1);
}

// ---------------- phase 2: exclusive scan of cnt_d -> offs ---------------
__global__ __launch_bounds__(256) void scan1(const int* __restrict__ cnt,
                                             int* __restrict__ offs,
                                             int* __restrict__ bsums) {
    __shared__ int lds[256];
    int t = threadIdx.x;
    int base = blockIdx.x * SCAN_ELEMS + t * 4;
    int v0 = (base + 0 < NN) ? cnt[base + 0] : 0;
    int v1 = (base + 1 < NN) ? cnt[base + 1] : 0;
    int v2 = (base + 2 < NN) ? cnt[base + 2] : 0;
    int v3 = (base + 3 < NN) ? cnt[base + 3] : 0;
    int s = v0 + v1 + v2 + v3;
    lds[t] = s;
    __syncthreads();
    int val = s;
    for (int off = 1; off < 256; off <<= 1) {
        int tmp = (t >= off) ? lds[t - off] : 0;
        __syncthreads();
        val += tmp;
        lds[t] = val;
        __syncthreads();
    }
    int ex = val - s;
    if (base + 0 < NN) offs[base + 0] = ex;
    if (base + 1 < NN) offs[base + 1] = ex + v0;
    if (base + 2 < NN) offs[base + 2] = ex + v0 + v1;
    if (base + 3 < NN) offs[base + 3] = ex + v0 + v1 + v2;
    if (t == 255) bsums[blockIdx.x] = val;
}

__global__ __launch_bounds__(64) void scan2(int* __restrict__ bsums) {
    __shared__ int lds[64];
    int t = threadIdx.x;
    int v = (t < NBLK_SCAN) ? bsums[t] : 0;
    lds[t] = v;
    __syncthreads();
    int val = v;
    for (int off = 1; off < 64; off <<= 1) {
        int tmp = (t >= off) ? lds[t - off] : 0;
        __syncthreads();
        val += tmp;
        lds[t] = val;
        __syncthreads();
    }
    if (t < NBLK_SCAN) bsums[t] = val - v;
}

__global__ __launch_bounds__(256) void scan3(int* __restrict__ offs,
                                             const int* __restrict__ bsums) {
    int i = blockIdx.x * 256 + threadIdx.x;
    if (i < NN) offs[i] += bsums[i >> 10];
    if (i == 0) offs[NN] = NE;
}

// ---------------- phase 3: bin edges by dst ------------------------------
__global__ __launch_bounds__(256) void fill_bins(const int* __restrict__ src,
                                                 const int* __restrict__ dst,
                                                 const int* __restrict__ et,
                                                 const int* __restrict__ offs,
                                                 int* __restrict__ cur,
                                                 int* __restrict__ ebin) {
    int e = blockIdx.x * 256 + threadIdx.x;
    if (e >= NE) return;
    int d = dst[e];
    int idx = offs[d] + atomicAdd(&cur[d], 1);
    ebin[idx] = (et[e] << 16) | src[e];   // src < 50000 < 2^16
}

// ---------------- prep: x fp32 -> bf16 -----------------------------------
__global__ __launch_bounds__(256) void convert_x(const float* __restrict__ x,
                                                 u16* __restrict__ xb) {
    int i = (blockIdx.x * 256 + threadIdx.x) * 4;
    if (i >= NN * D) return;
    float4 v = *(const float4*)(x + i);
    ushort4 o;
    o.x = f2bf(v.x); o.y = f2bf(v.y); o.z = f2bf(v.z); o.w = f2bf(v.w);
    *(ushort4*)(xb + i) = o;
}

// ---------------- prep: transpose weight/root -> bf16 [n][k] -------------
__global__ __launch_bounds__(256) void transpose_w(const float* __restrict__ weight,
                                                   const float* __restrict__ root,
                                                   u16* __restrict__ wt,
                                                   u16* __restrict__ rt) {
    int gid = blockIdx.x * 256 + threadIdx.x;
    if (gid >= (NR + 1) * D * D) return;
    int p = gid >> 14;            // plane 0..8
    int idx = gid & 16383;        // n*128 + k
    int n = idx >> 7, k = idx & 127;
    float v = (p < NR) ? weight[(size_t)p * D * D + k * D + n] : root[k * D + n];
    u16* dst = (p < NR) ? (wt + (size_t)p * D * D) : rt;
    dst[idx] = f2bf(v);
}

// ---------------- phase 4: per-dst aggregation -> bf16 means -------------
__global__ __launch_bounds__(128) void aggregate_kernel(const float* __restrict__ x,
                                                        const int* __restrict__ offs,
                                                        const int* __restrict__ ebin,
                                                        u16* __restrict__ sums) {
    __shared__ float acc[NR * D];
    __shared__ int   scnt[NR];
    __shared__ float sinv[NR];
    int n = blockIdx.x;
    int t = threadIdx.x;
    for (int i = t; i < NR * D; i += 128) acc[i] = 0.0f;
    if (t < NR) scnt[t] = 0;
    __syncthreads();
    int beg = offs[n], end = offs[n + 1];
    for (int p = beg; p < end; ++p) {
        int pk = ebin[p];
        int r  = pk >> 16;
        int s  = pk & 0xffff;
        if (t == 0) scnt[r]++;
        acc[r * D + t] += x[(size_t)s * D + t];   // coalesced 512B row read
    }
    __syncthreads();
    if (t < NR) sinv[t] = 1.0f / (float)(scnt[t] > 0 ? scnt[t] : 1);
    __syncthreads();
    for (int r = 0; r < NR; ++r)
        sums[((size_t)r * NN + n) * D + t] = f2bf(acc[r * D + t] * sinv[r]);
}

// ---------------- phase 5: fused MFMA GEMM -------------------------------
// out[n][c] = relu( Σ_k A[n][k] * B[k][c] + bias[c] ), K = 1152
// A plane 0 = xb (row-major [n][128]); planes 1..8 = sums rel r-1.
// B plane 0 = rt; planes 1..8 = wt — stored TRANSPOSED [c][k] so B-fragments
// are contiguous 16B ds_read_b128 (same pattern as A).
// BM=128, BN=128 (full), BK=32; 256 threads = 4 waves, each wave 64x64.
__global__ __launch_bounds__(256) void mfma_gemm(const u16* __restrict__ xb,
                                                 const u16* __restrict__ sums,
                                                 const u16* __restrict__ rt,
                                                 const u16* __restrict__ wt,
                                                 const float* __restrict__ bias,
                                                 float* __restrict__ out) {
    __shared__ u16 As[128 * 32];   // [row][k] rows of 64B
    __shared__ u16 Bs[128 * 32];   // [col][k] rows of 64B

    const int tid  = threadIdx.x;
    const int wave = tid >> 6;
    const int lane = tid & 63;
    const int wm   = (wave & 1) * 64;
    const int wn   = (wave >> 1) * 64;
    const int m0   = blockIdx.x * 128;

    const int srow = lane >> 2;          // 0..15 within a 16-row staging chunk
    const int sch  = lane & 3;           // 16B chunk within 64B row

    f32x4 acc[4][4];
#pragma unroll
    for (int i = 0; i < 4; ++i)
#pragma unroll
        for (int j = 0; j < 4; ++j) acc[i][j] = (f32x4){0.f, 0.f, 0.f, 0.f};

    for (int k0 = 0; k0 < KT; k0 += 32) {
        const int rpl = k0 >> 7;
        const int kof = k0 & 127;
        const u16* Ap = (rpl == 0) ? xb : sums + (size_t)(rpl - 1) * NN * D;
        const u16* Bp = (rpl == 0) ? rt : wt + (size_t)(rpl - 1) * D * D;

        __syncthreads();   // previous iter's frag reads done before overwrite
#pragma unroll
        for (int j = 0; j < 2; ++j) {
            int row = wave * 32 + j * 16 + srow;
            int ga  = m0 + row; if (ga > NN - 1) ga = NN - 1;   // clamp tail
            async_cp16(Ap + (size_t)ga * D + kof + sch * 8,
                       &As[(wave * 32 + j * 16) * 32]);
            async_cp16(Bp + (size_t)row * D + kof + sch * 8,
                       &Bs[(wave * 32 + j * 16) * 32]);
        }
        __syncthreads();   // drains vmcnt: staged tiles visible

        s16x8 af[4], bf[4];
        const int fr = lane & 15;
        const int fk = (lane >> 4) * 8;
#pragma unroll
        for (int mt = 0; mt < 4; ++mt)
            af[mt] = *(const s16x8*)&As[(wm + mt * 16 + fr) * 32 + fk];
#pragma unroll
        for (int nt = 0; nt < 4; ++nt)
            bf[nt] = *(const s16x8*)&Bs[(wn + nt * 16 + fr) * 32 + fk];
#pragma unroll
        for (int mt = 0; mt < 4; ++mt)
#pragma unroll
            for (int nt = 0; nt < 4; ++nt)
                acc[mt][nt] = __builtin_amdgcn_mfma_f32_16x16x32_bf16(
                    af[mt], bf[nt], acc[mt][nt], 0, 0, 0);
    }

    // epilogue: C/D layout col=lane&15, row=(lane>>4)*4+reg
    const int cl = lane & 15;
    const int rq = (lane >> 4) * 4;
#pragma unroll
    for (int nt = 0; nt < 4; ++nt) {
        int col = wn + nt * 16 + cl;
        float bv = bias[col];
#pragma unroll
        for (int mt = 0; mt < 4; ++mt) {
#pragma unroll
            for (int reg = 0; reg < 4; ++reg) {
                int n = m0 + wm + mt * 16 + rq + reg;
                if (n < NN) {
                    float v = acc[mt][nt][reg] + bv;
                    out[(size_t)n * D + col] = fmaxf(v, 0.0f);
                }
            }
        }
    }
}

extern "C" void kernel_launch(void* const* d_in, const int* in_sizes, int n_in,
                              void* d_out, int out_size, void* d_ws, size_t ws_size,
                              hipStream_t stream) {
    const float* x      = (const float*)d_in[0];
    const int*   ei     = (const int*)d_in[1];
    const int*   et     = (const int*)d_in[2];
    const float* weight = (const float*)d_in[3];
    const float* root   = (const float*)d_in[4];
    const float* bias   = (const float*)d_in[5];
    float* out = (float*)d_out;
    const int* srcv = ei;
    const int* dstv = ei + NE;

    // ws layout: [cnt_d NN][cur NN][offs NN+1][bsums 64][ebin NE] ints,
    // then u16: [xb NN*D][sums NR*NN*D][wt NR*D*D][rt D*D]   (~118.5 MB)
    int* cnt_d = (int*)d_ws;
    int* cur   = cnt_d + NN;
    int* offs  = cur + NN;
    int* bsums = offs + NN + 1;
    int* ebin  = bsums + 64;
    size_t fixed_b  = ((char*)(ebin + NE) - (char*)d_ws);
    size_t fixed_al = (fixed_b + 255) & ~(size_t)255;
    u16* xb   = (u16*)((char*)d_ws + fixed_al);
    u16* sums = xb + (size_t)NN * D;
    u16* wt   = sums + (size_t)NR * NN * D;
    u16* rt   = wt + (size_t)NR * D * D;

    hipMemsetAsync(cnt_d, 0, 2 * NN * sizeof(int), stream);
    count_dst<<<(NE + 255) / 256, 256, 0, stream>>>(dstv, cnt_d);
    scan1<<<NBLK_SCAN, 256, 0, stream>>>(cnt_d, offs, bsums);
    scan2<<<1, 64, 0, stream>>>(bsums);
    scan3<<<(NN + 255) / 256, 256, 0, stream>>>(offs, bsums);
    fill_bins<<<(NE + 255) / 256, 256, 0, stream>>>(srcv, dstv, et, offs, cur, ebin);

    convert_x<<<(NN * D / 4 + 255) / 256, 256, 0, stream>>>(x, xb);
    transpose_w<<<((NR + 1) * D * D + 255) / 256, 256, 0, stream>>>(weight, root, wt, rt);

    aggregate_kernel<<<NN, 128, 0, stream>>>(x, offs, ebin, sums);

    mfma_gemm<<<(NN + 127) / 128, 256, 0, stream>>>(xb, sums, rt, wt, bias, out);
}

// Round 4
// 277.585 us; speedup vs baseline: 4.9973x; 1.0078x over previous
//
#include <hip/hip_runtime.h>

constexpr int NN = 50000;   // nodes
constexpr int NE = 600000;  // edges
constexpr int D  = 128;     // features
constexpr int NR = 8;       // relations
constexpr int KT = (NR + 1) * D;   // 1152 total K (root plane + 8 relation planes)

constexpr int SCAN_ELEMS = 1024;
constexpr int NBLK_SCAN  = (NN + SCAN_ELEMS - 1) / SCAN_ELEMS;   // 49

typedef unsigned int   u32;
typedef unsigned short u16;
typedef float  f32x4 __attribute__((ext_vector_type(4)));
typedef short  s16x8 __attribute__((ext_vector_type(8)));

__device__ __forceinline__ u16 f2bf(float f) {
    u32 u = __float_as_uint(f);
    u32 r = (u + 0x7fffu + ((u >> 16) & 1u)) >> 16;   // RNE
    return (u16)r;
}

__device__ __forceinline__ void async_cp16(const void* g, void* l) {
    __builtin_amdgcn_global_load_lds(
        (const __attribute__((address_space(1))) u32*)g,
        (__attribute__((address_space(3))) u32*)l, 16, 0, 0);
}

// ---------------- phase 1: per-dst edge counts ---------------------------
__global__ __launch_bounds__(256) void count_dst(const int* __restrict__ dst,
                                                 int* __restrict__ cnt_d) {
    int e = blockIdx.x * 256 + threadIdx.x;
    if (e < NE) atomicAdd(&cnt_d[dst[e]], 1);
}

// ---------------- phase 2: exclusive scan of cnt_d -> offs ---------------
__global__ __launch_bounds__(256) void scan1(const int* __restrict__ cnt,
                                             int* __restrict__ offs,
                                             int* __restrict__ bsums) {
    __shared__ int lds[256];
    int t = threadIdx.x;
    int base = blockIdx.x * SCAN_ELEMS + t * 4;
    int v0 = (base + 0 < NN) ? cnt[base + 0] : 0;
    int v1 = (base + 1 < NN) ? cnt[base + 1] : 0;
    int v2 = (base + 2 < NN) ? cnt[base + 2] : 0;
    int v3 = (base + 3 < NN) ? cnt[base + 3] : 0;
    int s = v0 + v1 + v2 + v3;
    lds[t] = s;
    __syncthreads();
    int val = s;
    for (int off = 1; off < 256; off <<= 1) {
        int tmp = (t >= off) ? lds[t - off] : 0;
        __syncthreads();
        val += tmp;
        lds[t] = val;
        __syncthreads();
    }
    int ex = val - s;
    if (base + 0 < NN) offs[base + 0] = ex;
    if (base + 1 < NN) offs[base + 1] = ex + v0;
    if (base + 2 < NN) offs[base + 2] = ex + v0 + v1;
    if (base + 3 < NN) offs[base + 3] = ex + v0 + v1 + v2;
    if (t == 255) bsums[blockIdx.x] = val;
}

__global__ __launch_bounds__(64) void scan2(int* __restrict__ bsums) {
    __shared__ int lds[64];
    int t = threadIdx.x;
    int v = (t < NBLK_SCAN) ? bsums[t] : 0;
    lds[t] = v;
    __syncthreads();
    int val = v;
    for (int off = 1; off < 64; off <<= 1) {
        int tmp = (t >= off) ? lds[t - off] : 0;
        __syncthreads();
        val += tmp;
        lds[t] = val;
        __syncthreads();
    }
    if (t < NBLK_SCAN) bsums[t] = val - v;
}

__global__ __launch_bounds__(256) void scan3(int* __restrict__ offs,
                                             const int* __restrict__ bsums) {
    int i = blockIdx.x * 256 + threadIdx.x;
    if (i < NN) offs[i] += bsums[i >> 10];
    if (i == 0) offs[NN] = NE;
}

// ---------------- phase 3: bin edges by dst ------------------------------
__global__ __launch_bounds__(256) void fill_bins(const int* __restrict__ src,
                                                 const int* __restrict__ dst,
                                                 const int* __restrict__ et,
                                                 const int* __restrict__ offs,
                                                 int* __restrict__ cur,
                                                 int* __restrict__ ebin) {
    int e = blockIdx.x * 256 + threadIdx.x;
    if (e >= NE) return;
    int d = dst[e];
    int idx = offs[d] + atomicAdd(&cur[d], 1);
    ebin[idx] = (et[e] << 16) | src[e];   // src < 50000 < 2^16
}

// ---------------- prep: x fp32 -> bf16 -----------------------------------
__global__ __launch_bounds__(256) void convert_x(const float* __restrict__ x,
                                                 u16* __restrict__ xb) {
    int i = (blockIdx.x * 256 + threadIdx.x) * 4;
    if (i >= NN * D) return;
    float4 v = *(const float4*)(x + i);
    ushort4 o;
    o.x = f2bf(v.x); o.y = f2bf(v.y); o.z = f2bf(v.z); o.w = f2bf(v.w);
    *(ushort4*)(xb + i) = o;
}

// ---------------- prep: transpose weight/root -> bf16 [n][k] -------------
__global__ __launch_bounds__(256) void transpose_w(const float* __restrict__ weight,
                                                   const float* __restrict__ root,
                                                   u16* __restrict__ wt,
                                                   u16* __restrict__ rt) {
    int gid = blockIdx.x * 256 + threadIdx.x;
    if (gid >= (NR + 1) * D * D) return;
    int p = gid >> 14;            // plane 0..8
    int idx = gid & 16383;        // n*128 + k
    int n = idx >> 7, k = idx & 127;
    float v = (p < NR) ? weight[(size_t)p * D * D + k * D + n] : root[k * D + n];
    u16* dst = (p < NR) ? (wt + (size_t)p * D * D) : rt;
    dst[idx] = f2bf(v);
}

// ---------------- phase 4: per-dst aggregation (register acc) ------------
// one block per dst node; 4 quarters of 32 lanes; quarter q takes edges
// beg+q, beg+q+4, ... Each lane owns 4 feature columns; relation dispatch is
// 8 predicated FMAs into register accumulators (no LDS in the edge loop, 4
// independent 512B row loads in flight per block). One LDS cross-quarter
// reduction at the end.
__global__ __launch_bounds__(128) void aggregate_kernel(const float* __restrict__ x,
                                                        const int* __restrict__ offs,
                                                        const int* __restrict__ ebin,
                                                        u16* __restrict__ sums) {
    __shared__ float lacc[4][NR][D];   // 16 KB: per-quarter partials
    __shared__ float lcn[4][NR];
    __shared__ float sinv[NR];

    const int n = blockIdx.x;
    const int t = threadIdx.x;
    const int q = t >> 5;             // quarter 0..3
    const int c = (t & 31) << 2;      // column base 0,4,...,124

    float acc[NR][4];
    float cn[NR];
#pragma unroll
    for (int r = 0; r < NR; ++r) {
        cn[r] = 0.0f;
#pragma unroll
        for (int j = 0; j < 4; ++j) acc[r][j] = 0.0f;
    }

    const int beg = offs[n], end = offs[n + 1];
    for (int p = beg + q; p < end; p += 4) {
        int pk = ebin[p];
        int er = pk >> 16;
        int s  = pk & 0xffff;
        float4 v = *(const float4*)(x + (size_t)s * D + c);
#pragma unroll
        for (int r = 0; r < NR; ++r) {
            float m = (er == r) ? 1.0f : 0.0f;
            cn[r] += m;
            acc[r][0] += m * v.x;
            acc[r][1] += m * v.y;
            acc[r][2] += m * v.z;
            acc[r][3] += m * v.w;
        }
    }

#pragma unroll
    for (int r = 0; r < NR; ++r)
        *(float4*)&lacc[q][r][c] = *(const float4*)acc[r];
    if ((t & 31) == 0) {
#pragma unroll
        for (int r = 0; r < NR; ++r) lcn[q][r] = cn[r];
    }
    __syncthreads();
    if (t < NR) {
        float tot = lcn[0][t] + lcn[1][t] + lcn[2][t] + lcn[3][t];
        sinv[t] = 1.0f / fmaxf(tot, 1.0f);
    }
    __syncthreads();

#pragma unroll
    for (int r = 0; r < NR; ++r) {
        float s = lacc[0][r][t] + lacc[1][r][t] + lacc[2][r][t] + lacc[3][r][t];
        sums[((size_t)r * NN + n) * D + t] = f2bf(s * sinv[r]);
    }
}

// ---------------- phase 5: fused MFMA GEMM -------------------------------
// out[n][c] = relu( Σ_k A[n][k] * B[k][c] + bias[c] ), K = 1152
// BM=128, BN=128 (full), BK=32; 256 threads = 4 waves, each wave 64x64.
__global__ __launch_bounds__(256) void mfma_gemm(const u16* __restrict__ xb,
                                                 const u16* __restrict__ sums,
                                                 const u16* __restrict__ rt,
                                                 const u16* __restrict__ wt,
                                                 const float* __restrict__ bias,
                                                 float* __restrict__ out) {
    __shared__ u16 As[128 * 32];   // [row][k] rows of 64B
    __shared__ u16 Bs[128 * 32];   // [col][k] rows of 64B

    const int tid  = threadIdx.x;
    const int wave = tid >> 6;
    const int lane = tid & 63;
    const int wm   = (wave & 1) * 64;
    const int wn   = (wave >> 1) * 64;
    const int m0   = blockIdx.x * 128;

    const int srow = lane >> 2;
    const int sch  = lane & 3;
    (void)srow; (void)sch;

    f32x4 acc[4][4];
#pragma unroll
    for (int i = 0; i < 4; ++i)
#pragma unroll
        for (int j = 0; j < 4; ++j) acc[i][j] = (f32x4){0.f, 0.f, 0.f, 0.f};

    for (int k0 = 0; k0 < KT; k0 += 32) {
        const int rpl = k0 >> 7;
        const int kof = k0 & 127;
        const u16* Ap = (rpl == 0) ? xb : sums + (size_t)(rpl - 1) * NN * D;
        const u16* Bp = (rpl == 0) ? rt : wt + (size_t)(rpl - 1) * D * D;

        __syncthreads();
#pragma unroll
        for (int j = 0; j < 2; ++j) {
            int row = wave * 32 + j * 16 + (lane >> 2);
            int ga  = m0 + row; if (ga > NN - 1) ga = NN - 1;   // clamp tail
            async_cp16(Ap + (size_t)ga * D + kof + (lane & 3) * 8,
                       &As[(wave * 32 + j * 16) * 32]);
            async_cp16(Bp + (size_t)row * D + kof + (lane & 3) * 8,
                       &Bs[(wave * 32 + j * 16) * 32]);
        }
        __syncthreads();

        s16x8 af[4], bf[4];
        const int fr = lane & 15;
        const int fk = (lane >> 4) * 8;
#pragma unroll
        for (int mt = 0; mt < 4; ++mt)
            af[mt] = *(const s16x8*)&As[(wm + mt * 16 + fr) * 32 + fk];
#pragma unroll
        for (int nt = 0; nt < 4; ++nt)
            bf[nt] = *(const s16x8*)&Bs[(wn + nt * 16 + fr) * 32 + fk];
#pragma unroll
        for (int mt = 0; mt < 4; ++mt)
#pragma unroll
            for (int nt = 0; nt < 4; ++nt)
                acc[mt][nt] = __builtin_amdgcn_mfma_f32_16x16x32_bf16(
                    af[mt], bf[nt], acc[mt][nt], 0, 0, 0);
    }

    // epilogue: C/D layout col=lane&15, row=(lane>>4)*4+reg
    const int cl = lane & 15;
    const int rq = (lane >> 4) * 4;
#pragma unroll
    for (int nt = 0; nt < 4; ++nt) {
        int col = wn + nt * 16 + cl;
        float bv = bias[col];
#pragma unroll
        for (int mt = 0; mt < 4; ++mt) {
#pragma unroll
            for (int reg = 0; reg < 4; ++reg) {
                int n = m0 + wm + mt * 16 + rq + reg;
                if (n < NN) {
                    float v = acc[mt][nt][reg] + bv;
                    out[(size_t)n * D + col] = fmaxf(v, 0.0f);
                }
            }
        }
    }
}

extern "C" void kernel_launch(void* const* d_in, const int* in_sizes, int n_in,
                              void* d_out, int out_size, void* d_ws, size_t ws_size,
                              hipStream_t stream) {
    const float* x      = (const float*)d_in[0];
    const int*   ei     = (const int*)d_in[1];
    const int*   et     = (const int*)d_in[2];
    const float* weight = (const float*)d_in[3];
    const float* root   = (const float*)d_in[4];
    const float* bias   = (const float*)d_in[5];
    float* out = (float*)d_out;
    const int* srcv = ei;
    const int* dstv = ei + NE;

    // ws layout: [cnt_d NN][cur NN][offs NN+1][bsums 64][ebin NE] ints,
    // then u16: [xb NN*D][sums NR*NN*D][wt NR*D*D][rt D*D]   (~118.5 MB)
    int* cnt_d = (int*)d_ws;
    int* cur   = cnt_d + NN;
    int* offs  = cur + NN;
    int* bsums = offs + NN + 1;
    int* ebin  = bsums + 64;
    size_t fixed_b  = ((char*)(ebin + NE) - (char*)d_ws);
    size_t fixed_al = (fixed_b + 255) & ~(size_t)255;
    u16* xb   = (u16*)((char*)d_ws + fixed_al);
    u16* sums = xb + (size_t)NN * D;
    u16* wt   = sums + (size_t)NR * NN * D;
    u16* rt   = wt + (size_t)NR * D * D;

    hipMemsetAsync(cnt_d, 0, 2 * NN * sizeof(int), stream);
    count_dst<<<(NE + 255) / 256, 256, 0, stream>>>(dstv, cnt_d);
    scan1<<<NBLK_SCAN, 256, 0, stream>>>(cnt_d, offs, bsums);
    scan2<<<1, 64, 0, stream>>>(bsums);
    scan3<<<(NN + 255) / 256, 256, 0, stream>>>(offs, bsums);
    fill_bins<<<(NE + 255) / 256, 256, 0, stream>>>(srcv, dstv, et, offs, cur, ebin);

    convert_x<<<(NN * D / 4 + 255) / 256, 256, 0, stream>>>(x, xb);
    transpose_w<<<((NR + 1) * D * D + 255) / 256, 256, 0, stream>>>(weight, root, wt, rt);

    aggregate_kernel<<<NN, 128, 0, stream>>>(x, offs, ebin, sums);

    mfma_gemm<<<(NN + 127) / 128, 256, 0, stream>>>(xb, sums, rt, wt, bias, out);
}

// Round 5
// 258.589 us; speedup vs baseline: 5.3644x; 1.0735x over previous
//
#include <hip/hip_runtime.h>

constexpr int NN = 50000;   // nodes
constexpr int NE = 600000;  // edges
constexpr int D  = 128;     // features
constexpr int NR = 8;       // relations
constexpr int KT = (NR + 1) * D;   // 1152 total K (root plane + 8 relation planes)

constexpr int SCAN_ELEMS = 1024;
constexpr int NBLK_SCAN  = (NN + SCAN_ELEMS - 1) / SCAN_ELEMS;   // 49

typedef unsigned int   u32;
typedef unsigned short u16;
typedef float  f32x4 __attribute__((ext_vector_type(4)));
typedef short  s16x8 __attribute__((ext_vector_type(8)));

__device__ __forceinline__ u16 f2bf(float f) {
    u32 u = __float_as_uint(f);
    u32 r = (u + 0x7fffu + ((u >> 16) & 1u)) >> 16;   // RNE
    return (u16)r;
}

__device__ __forceinline__ void async_cp16(const void* g, void* l) {
    __builtin_amdgcn_global_load_lds(
        (const __attribute__((address_space(1))) u32*)g,
        (__attribute__((address_space(3))) u32*)l, 16, 0, 0);
}

// ---------------- phase 1: per-dst edge counts ---------------------------
__global__ __launch_bounds__(256) void count_dst(const int* __restrict__ dst,
                                                 int* __restrict__ cnt_d) {
    int e = blockIdx.x * 256 + threadIdx.x;
    if (e < NE) atomicAdd(&cnt_d[dst[e]], 1);
}

// ---------------- phase 2: exclusive scan of cnt_d -> offs ---------------
__global__ __launch_bounds__(256) void scan1(const int* __restrict__ cnt,
                                             int* __restrict__ offs,
                                             int* __restrict__ bsums) {
    __shared__ int lds[256];
    int t = threadIdx.x;
    int base = blockIdx.x * SCAN_ELEMS + t * 4;
    int v0 = (base + 0 < NN) ? cnt[base + 0] : 0;
    int v1 = (base + 1 < NN) ? cnt[base + 1] : 0;
    int v2 = (base + 2 < NN) ? cnt[base + 2] : 0;
    int v3 = (base + 3 < NN) ? cnt[base + 3] : 0;
    int s = v0 + v1 + v2 + v3;
    lds[t] = s;
    __syncthreads();
    int val = s;
    for (int off = 1; off < 256; off <<= 1) {
        int tmp = (t >= off) ? lds[t - off] : 0;
        __syncthreads();
        val += tmp;
        lds[t] = val;
        __syncthreads();
    }
    int ex = val - s;
    if (base + 0 < NN) offs[base + 0] = ex;
    if (base + 1 < NN) offs[base + 1] = ex + v0;
    if (base + 2 < NN) offs[base + 2] = ex + v0 + v1;
    if (base + 3 < NN) offs[base + 3] = ex + v0 + v1 + v2;
    if (t == 255) bsums[blockIdx.x] = val;
}

__global__ __launch_bounds__(64) void scan2(int* __restrict__ bsums) {
    __shared__ int lds[64];
    int t = threadIdx.x;
    int v = (t < NBLK_SCAN) ? bsums[t] : 0;
    lds[t] = v;
    __syncthreads();
    int val = v;
    for (int off = 1; off < 64; off <<= 1) {
        int tmp = (t >= off) ? lds[t - off] : 0;
        __syncthreads();
        val += tmp;
        lds[t] = val;
        __syncthreads();
    }
    if (t < NBLK_SCAN) bsums[t] = val - v;
}

__global__ __launch_bounds__(256) void scan3(int* __restrict__ offs,
                                             const int* __restrict__ bsums) {
    int i = blockIdx.x * 256 + threadIdx.x;
    if (i < NN) offs[i] += bsums[i >> 10];
    if (i == 0) offs[NN] = NE;
}

// ---------------- phase 3: bin edges by dst ------------------------------
__global__ __launch_bounds__(256) void fill_bins(const int* __restrict__ src,
                                                 const int* __restrict__ dst,
                                                 const int* __restrict__ et,
                                                 const int* __restrict__ offs,
                                                 int* __restrict__ cur,
                                                 int* __restrict__ ebin) {
    int e = blockIdx.x * 256 + threadIdx.x;
    if (e >= NE) return;
    int d = dst[e];
    int idx = offs[d] + atomicAdd(&cur[d], 1);
    ebin[idx] = (et[e] << 16) | src[e];   // src < 50000 < 2^16
}

// ---------------- prep: x fp32 -> bf16 -----------------------------------
__global__ __launch_bounds__(256) void convert_x(const float* __restrict__ x,
                                                 u16* __restrict__ xb) {
    int i = (blockIdx.x * 256 + threadIdx.x) * 4;
    if (i >= NN * D) return;
    float4 v = *(const float4*)(x + i);
    ushort4 o;
    o.x = f2bf(v.x); o.y = f2bf(v.y); o.z = f2bf(v.z); o.w = f2bf(v.w);
    *(ushort4*)(xb + i) = o;
}

// ---------------- prep: transpose weight/root -> bf16 [n][k] -------------
__global__ __launch_bounds__(256) void transpose_w(const float* __restrict__ weight,
                                                   const float* __restrict__ root,
                                                   u16* __restrict__ wt,
                                                   u16* __restrict__ rt) {
    int gid = blockIdx.x * 256 + threadIdx.x;
    if (gid >= (NR + 1) * D * D) return;
    int p = gid >> 14;            // plane 0..8
    int idx = gid & 16383;        // n*128 + k
    int n = idx >> 7, k = idx & 127;
    float v = (p < NR) ? weight[(size_t)p * D * D + k * D + n] : root[k * D + n];
    u16* dst = (p < NR) ? (wt + (size_t)p * D * D) : rt;
    dst[idx] = f2bf(v);
}

// ---------------- phase 4: per-dst aggregation (wave-per-node) -----------
// One 64-lane wave per node, ZERO LDS. Row gather from bf16 xb: 256B/row =
// one u32 per lane (2 packed bf16 -> 2 f32 by bit tricks). Edge decode is
// wave-uniform -> readfirstlane -> scalar branch chain (no divergence);
// relation counts accumulate scalar-side. 4 scalar decodes then 4 row loads
// issued back-to-back -> 4 rows in flight per wave; ~40 VGPR, no LDS ->
// full occupancy -> ~128 rows in flight per CU.
__global__ __launch_bounds__(128) void aggregate_kernel(const u32* __restrict__ xw,
                                                        const int* __restrict__ offs,
                                                        const int* __restrict__ ebin,
                                                        u32* __restrict__ sw) {
    const int lane = threadIdx.x & 63;
    const int n = blockIdx.x * 2 + (threadIdx.x >> 6);
    if (n >= NN) return;
    const int beg = __builtin_amdgcn_readfirstlane(offs[n]);
    const int end = __builtin_amdgcn_readfirstlane(offs[n + 1]);

    float acc[NR][2];
    int cnt[NR];
#pragma unroll
    for (int r = 0; r < NR; ++r) { acc[r][0] = 0.f; acc[r][1] = 0.f; cnt[r] = 0; }

#define ACC_EDGE(ER, LO, HI)                                        \
    switch (ER) {                                                   \
    case 0: acc[0][0] += LO; acc[0][1] += HI; ++cnt[0]; break;      \
    case 1: acc[1][0] += LO; acc[1][1] += HI; ++cnt[1]; break;      \
    case 2: acc[2][0] += LO; acc[2][1] += HI; ++cnt[2]; break;      \
    case 3: acc[3][0] += LO; acc[3][1] += HI; ++cnt[3]; break;      \
    case 4: acc[4][0] += LO; acc[4][1] += HI; ++cnt[4]; break;      \
    case 5: acc[5][0] += LO; acc[5][1] += HI; ++cnt[5]; break;      \
    case 6: acc[6][0] += LO; acc[6][1] += HI; ++cnt[6]; break;      \
    default: acc[7][0] += LO; acc[7][1] += HI; ++cnt[7]; break;     \
    }

    int p = beg;
    for (; p + 4 <= end; p += 4) {
        int pk0 = __builtin_amdgcn_readfirstlane(ebin[p + 0]);
        int pk1 = __builtin_amdgcn_readfirstlane(ebin[p + 1]);
        int pk2 = __builtin_amdgcn_readfirstlane(ebin[p + 2]);
        int pk3 = __builtin_amdgcn_readfirstlane(ebin[p + 3]);
        // issue all 4 row loads before any consumption
        u32 v0 = xw[(size_t)(pk0 & 0xffff) * 64 + lane];
        u32 v1 = xw[(size_t)(pk1 & 0xffff) * 64 + lane];
        u32 v2 = xw[(size_t)(pk2 & 0xffff) * 64 + lane];
        u32 v3 = xw[(size_t)(pk3 & 0xffff) * 64 + lane];
        float l0 = __uint_as_float(v0 << 16), h0 = __uint_as_float(v0 & 0xffff0000u);
        float l1 = __uint_as_float(v1 << 16), h1 = __uint_as_float(v1 & 0xffff0000u);
        float l2 = __uint_as_float(v2 << 16), h2 = __uint_as_float(v2 & 0xffff0000u);
        float l3 = __uint_as_float(v3 << 16), h3 = __uint_as_float(v3 & 0xffff0000u);
        ACC_EDGE(pk0 >> 16, l0, h0)
        ACC_EDGE(pk1 >> 16, l1, h1)
        ACC_EDGE(pk2 >> 16, l2, h2)
        ACC_EDGE(pk3 >> 16, l3, h3)
    }
    for (; p < end; ++p) {
        int pk = __builtin_amdgcn_readfirstlane(ebin[p]);
        u32 v = xw[(size_t)(pk & 0xffff) * 64 + lane];
        float lo = __uint_as_float(v << 16), hi = __uint_as_float(v & 0xffff0000u);
        ACC_EDGE(pk >> 16, lo, hi)
    }
#undef ACC_EDGE

#pragma unroll
    for (int r = 0; r < NR; ++r) {
        float inv = 1.0f / (float)(cnt[r] > 0 ? cnt[r] : 1);
        u32 lo16 = f2bf(acc[r][0] * inv);
        u32 hi16 = f2bf(acc[r][1] * inv);
        sw[((size_t)r * NN + n) * 64 + lane] = lo16 | (hi16 << 16);
    }
}

// ---------------- phase 5: fused MFMA GEMM -------------------------------
// out[n][c] = relu( Σ_k A[n][k] * B[k][c] + bias[c] ), K = 1152
// BM=128, BN=128 (full), BK=32; 256 threads = 4 waves, each wave 64x64.
__global__ __launch_bounds__(256) void mfma_gemm(const u16* __restrict__ xb,
                                                 const u16* __restrict__ sums,
                                                 const u16* __restrict__ rt,
                                                 const u16* __restrict__ wt,
                                                 const float* __restrict__ bias,
                                                 float* __restrict__ out) {
    __shared__ u16 As[128 * 32];   // [row][k] rows of 64B
    __shared__ u16 Bs[128 * 32];   // [col][k] rows of 64B

    const int tid  = threadIdx.x;
    const int wave = tid >> 6;
    const int lane = tid & 63;
    const int wm   = (wave & 1) * 64;
    const int wn   = (wave >> 1) * 64;
    const int m0   = blockIdx.x * 128;

    f32x4 acc[4][4];
#pragma unroll
    for (int i = 0; i < 4; ++i)
#pragma unroll
        for (int j = 0; j < 4; ++j) acc[i][j] = (f32x4){0.f, 0.f, 0.f, 0.f};

    for (int k0 = 0; k0 < KT; k0 += 32) {
        const int rpl = k0 >> 7;
        const int kof = k0 & 127;
        const u16* Ap = (rpl == 0) ? xb : sums + (size_t)(rpl - 1) * NN * D;
        const u16* Bp = (rpl == 0) ? rt : wt + (size_t)(rpl - 1) * D * D;

        __syncthreads();
#pragma unroll
        for (int j = 0; j < 2; ++j) {
            int row = wave * 32 + j * 16 + (lane >> 2);
            int ga  = m0 + row; if (ga > NN - 1) ga = NN - 1;   // clamp tail
            async_cp16(Ap + (size_t)ga * D + kof + (lane & 3) * 8,
                       &As[(wave * 32 + j * 16) * 32]);
            async_cp16(Bp + (size_t)row * D + kof + (lane & 3) * 8,
                       &Bs[(wave * 32 + j * 16) * 32]);
        }
        __syncthreads();

        s16x8 af[4], bf[4];
        const int fr = lane & 15;
        const int fk = (lane >> 4) * 8;
#pragma unroll
        for (int mt = 0; mt < 4; ++mt)
            af[mt] = *(const s16x8*)&As[(wm + mt * 16 + fr) * 32 + fk];
#pragma unroll
        for (int nt = 0; nt < 4; ++nt)
            bf[nt] = *(const s16x8*)&Bs[(wn + nt * 16 + fr) * 32 + fk];
#pragma unroll
        for (int mt = 0; mt < 4; ++mt)
#pragma unroll
            for (int nt = 0; nt < 4; ++nt)
                acc[mt][nt] = __builtin_amdgcn_mfma_f32_16x16x32_bf16(
                    af[mt], bf[nt], acc[mt][nt], 0, 0, 0);
    }

    // epilogue: C/D layout col=lane&15, row=(lane>>4)*4+reg
    const int cl = lane & 15;
    const int rq = (lane >> 4) * 4;
#pragma unroll
    for (int nt = 0; nt < 4; ++nt) {
        int col = wn + nt * 16 + cl;
        float bv = bias[col];
#pragma unroll
        for (int mt = 0; mt < 4; ++mt) {
#pragma unroll
            for (int reg = 0; reg < 4; ++reg) {
                int n = m0 + wm + mt * 16 + rq + reg;
                if (n < NN) {
                    float v = acc[mt][nt][reg] + bv;
                    out[(size_t)n * D + col] = fmaxf(v, 0.0f);
                }
            }
        }
    }
}

extern "C" void kernel_launch(void* const* d_in, const int* in_sizes, int n_in,
                              void* d_out, int out_size, void* d_ws, size_t ws_size,
                              hipStream_t stream) {
    const float* x      = (const float*)d_in[0];
    const int*   ei     = (const int*)d_in[1];
    const int*   et     = (const int*)d_in[2];
    const float* weight = (const float*)d_in[3];
    const float* root   = (const float*)d_in[4];
    const float* bias   = (const float*)d_in[5];
    float* out = (float*)d_out;
    const int* srcv = ei;
    const int* dstv = ei + NE;

    // ws layout: [cnt_d NN][cur NN][offs NN+1][bsums 64][ebin NE] ints,
    // then u16: [xb NN*D][sums NR*NN*D][wt NR*D*D][rt D*D]   (~118.5 MB)
    int* cnt_d = (int*)d_ws;
    int* cur   = cnt_d + NN;
    int* offs  = cur + NN;
    int* bsums = offs + NN + 1;
    int* ebin  = bsums + 64;
    size_t fixed_b  = ((char*)(ebin + NE) - (char*)d_ws);
    size_t fixed_al = (fixed_b + 255) & ~(size_t)255;
    u16* xb   = (u16*)((char*)d_ws + fixed_al);
    u16* sums = xb + (size_t)NN * D;
    u16* wt   = sums + (size_t)NR * NN * D;
    u16* rt   = wt + (size_t)NR * D * D;

    hipMemsetAsync(cnt_d, 0, 2 * NN * sizeof(int), stream);
    count_dst<<<(NE + 255) / 256, 256, 0, stream>>>(dstv, cnt_d);
    scan1<<<NBLK_SCAN, 256, 0, stream>>>(cnt_d, offs, bsums);
    scan2<<<1, 64, 0, stream>>>(bsums);
    scan3<<<(NN + 255) / 256, 256, 0, stream>>>(offs, bsums);
    fill_bins<<<(NE + 255) / 256, 256, 0, stream>>>(srcv, dstv, et, offs, cur, ebin);

    convert_x<<<(NN * D / 4 + 255) / 256, 256, 0, stream>>>(x, xb);
    transpose_w<<<((NR + 1) * D * D + 255) / 256, 256, 0, stream>>>(weight, root, wt, rt);

    aggregate_kernel<<<(NN + 1) / 2, 128, 0, stream>>>((const u32*)xb, offs, ebin, (u32*)sums);

    mfma_gemm<<<(NN + 127) / 128, 256, 0, stream>>>(xb, sums, rt, wt, bias, out);
}